// Round 5
// baseline (858.893 us; speedup 1.0000x reference)
//
#include <hip/hip_runtime.h>
#include <hip/hip_fp16.h>

// ---------------------------------------------------------------------------
// VQFFN1: out = softmax(rmsnorm(x) @ rmsnorm(w)^T) @ w
//   x: [16384,1024] fp32   w: [4096,1024] fp32   out: [16384,1024] fp32
// fp32 scores; GEMM2 plain fp16 + split-K + f32 HW atomics.
// R2: XOR-swizzled LDS (bank conflicts 3.8e7 -> 0).
// R5: S = (xh + xl) @ wh^T; shared WH tile + b-frags across both passes.
// R7 FAILED: gemm2 split-K 4 alone (occupancy not the lever).
// R8: gemm2 BK 64->128: 650us; gemm1 at MfmaUtil 43% (2-barrier drain).
// R9/R10 FAILED: two fine-phase (4-ph / 8-ph m201-style) gemm1 ports landed
//     at 40%/34% MfmaUtil -- worse than plain. Barrier density + hot waits.
// R11: T3-MINIMAL on both GEMMs: stage issued BEFORE compute, drains AGED
//     >= 1 full compute phase, 1-2 barriers per K-tile (not per sub-phase).
//     gemm1: 256x256xBK64, 512thr, wave 128x64, LDS 128KB = B dbuf + Ah/Al
//       single. Phase A(hi): STG Al(i),B(i+1); 64 MFMA; vmcnt(4); bar.
//       Phase B(lo): STG Ah(i+1); 64 MFMA (b reg-cached); vmcnt(0) aged; bar.
//     gemm2: 256x256xBK64 dbuf, 512thr, split-K=4, grid 16x4x4=256=1/CU.
//       Per iter: STG nxt(8); 64 MFMA; vmcnt(0) aged; bar.
// ---------------------------------------------------------------------------

#define D_MODEL 1024
#define D_FF    4096
#define M_ROWS  16384
#define MC      4096

typedef _Float16 half8 __attribute__((ext_vector_type(8)));
typedef _Float16 half4 __attribute__((ext_vector_type(4)));
typedef float    floatx4 __attribute__((ext_vector_type(4)));

// async global->LDS, 16B/lane; LDS dst = wave-uniform base + lane*16 (m97)
__device__ __forceinline__ void gld_lds16(const void* g, void* l) {
  __builtin_amdgcn_global_load_lds(
      (const __attribute__((address_space(1))) void*)g,
      (__attribute__((address_space(3))) void*)l, 16, 0, 0);
}

// ---------------------------------------------------------------------------
// rmsnorm (fp32 in) + hi/lo fp16 split. One wave per row of 1024.
// ---------------------------------------------------------------------------
#define MB_X (M_ROWS / 4)
#define MB_W (D_FF / 4)
__global__ __launch_bounds__(256) void rmsnorm_split_kernel(
    const float* __restrict__ X, _Float16* __restrict__ XH,
    _Float16* __restrict__ XL, const float* __restrict__ W,
    _Float16* __restrict__ WH, _Float16* __restrict__ WL) {
  const int lane = threadIdx.x & 63;
  const bool isW = blockIdx.x >= MB_X;
  const long row = (long)(isW ? blockIdx.x - MB_X : blockIdx.x) * 4 +
                   (threadIdx.x >> 6);
  const float* x = (isW ? W : X) + row * D_MODEL;
  _Float16* YH = (isW ? WH : XH) + row * D_MODEL;
  _Float16* YL = (isW ? WL : XL) + row * D_MODEL;

  float v[16];
  float ss = 0.f;
#pragma unroll
  for (int s = 0; s < 4; s++) {
    const float4 f = *(const float4*)(x + s * 256 + lane * 4);
    v[s * 4 + 0] = f.x; v[s * 4 + 1] = f.y;
    v[s * 4 + 2] = f.z; v[s * 4 + 3] = f.w;
    ss += f.x * f.x + f.y * f.y + f.z * f.z + f.w * f.w;
  }
#pragma unroll
  for (int off = 32; off >= 1; off >>= 1) ss += __shfl_xor(ss, off);
  const float inv = rsqrtf(ss * (1.0f / D_MODEL) + 1e-6f);
#pragma unroll
  for (int s = 0; s < 4; s++) {
    half4 h, l;
#pragma unroll
    for (int j = 0; j < 4; j++) {
      const float t = v[s * 4 + j] * inv;
      const _Float16 hi = (_Float16)t;
      h[j] = hi;
      l[j] = (_Float16)(t - (float)hi);
    }
    *(half4*)(YH + s * 256 + lane * 4) = h;
    *(half4*)(YL + s * 256 + lane * 4) = l;
  }
}

// ---------------------------------------------------------------------------
// transpose w [4096,1024] fp32 -> wT [1024,4096] fp16 (unnormalized, GEMM2 B)
// ---------------------------------------------------------------------------
__global__ __launch_bounds__(256) void transpose_kernel(
    const float* __restrict__ W, _Float16* __restrict__ WT) {
  __shared__ _Float16 tile[32][33];
  const int tx = threadIdx.x & 31;
  const int ty = threadIdx.x >> 5;  // 0..7
  const int d0 = blockIdx.x * 32;
  const int c0 = blockIdx.y * 32;
#pragma unroll
  for (int i = 0; i < 32; i += 8)
    tile[ty + i][tx] = (_Float16)W[(long)(c0 + ty + i) * D_MODEL + d0 + tx];
  __syncthreads();
#pragma unroll
  for (int i = 0; i < 32; i += 8)
    WT[(long)(d0 + ty + i) * D_FF + c0 + tx] = tile[tx][ty + i];
}

// ---------------------------------------------------------------------------
// GEMM1: S[4096,4096] fp32 = (xh + xl) @ wh^T over K=1024.  (R11)
// LDS tiles [row][64] f16, R2 XOR swizzle: slot s holds global k-slot
// s ^ (row&7) via pre-swizzled global source col; fragment reads XOR the
// k-slot with m16&7 -> conflict-free ds_read_b128 (measured 0).
// Ledger (per-thread gld counts, queue oldest-first):
//   prologue: B(0) 4, Ah(0) 4 -> vmcnt(0), bar.
//   phase A(i): issue Al(i) 4 then B(i+1) 4; compute hi; vmcnt(4) drains
//     Al(i) (age ~1 phase), leaves B flying; bar. (last iter: vmcnt(0))
//   phase B(i): issue Ah(i+1) 4; compute lo; vmcnt(0) -- outstanding are
//     B(i+1) (~1.5 phases) + Ah(i+1) (~0.9 phase): aged drain; bar.
// Overwrite safety: a tile's readers consume via MFMA (compiler lgkm-drains)
// before the barrier that precedes its re-staging.
// ---------------------------------------------------------------------------
__global__ __launch_bounds__(512, 2) void gemm1_kernel(
    const _Float16* __restrict__ XH, const _Float16* __restrict__ XL,
    const _Float16* __restrict__ WH, float* __restrict__ S) {
  __shared__ _Float16 Bs2[2][256 * 64];  // 64 KB (dbuf)
  __shared__ _Float16 AhT[256 * 64];     // 32 KB (single)
  __shared__ _Float16 AlT[256 * 64];     // 32 KB (single)
  const int tid = threadIdx.x;
  const int lane = tid & 63, wave = tid >> 6;

  // XCD-chunked bijective swizzle (256 blocks)
  const int bid = blockIdx.y * 16 + blockIdx.x;
  const int lg = ((bid & 7) << 5) | (bid >> 3);
  const int by = lg >> 4, bx = lg & 15;
  const long rowBase = (long)by * 256;
  const long colBase = (long)bx * 256;

  // staging: thread t covers (row = r*64 + (t>>3), slot = t&7) of a tile
  const int srow = tid >> 3;                       // 0..63
  const int scol = ((tid & 7) ^ (srow & 7)) * 8;   // pre-swizzled source col
  const _Float16* Bg  = WH + (colBase + srow) * (long)D_MODEL + scol;
  const _Float16* Ahg = XH + (rowBase + srow) * (long)D_MODEL + scol;
  const _Float16* Alg = XL + (rowBase + srow) * (long)D_MODEL + scol;
  const int dstOff = tid * 8;  // f16 units; round r adds r*4096

  const int wr = wave >> 2, wc = wave & 3;  // wave tile: 128 rows x 64 cols
  const int m16 = lane & 15, q = lane >> 4, mx7 = m16 & 7;
  const int aBase = wr * 128, bBase = wc * 64;

  floatx4 acc[8][4] = {};
  half8 b[2][4];  // reg-cached across hi->lo

#define STG(G, T, R, KT) \
  gld_lds16((G) + (long)(R)*64 * D_MODEL + (KT), &(T)[(R)*4096 + dstOff]);
#define BAR() __builtin_amdgcn_s_barrier()
#define SCHED0() __builtin_amdgcn_sched_barrier(0)

  // ---- prologue ----
#pragma unroll
  for (int r = 0; r < 4; r++) STG(Bg, Bs2[0], r, 0);
#pragma unroll
  for (int r = 0; r < 4; r++) STG(Ahg, AhT, r, 0);
  asm volatile("s_waitcnt vmcnt(0)" ::: "memory");
  BAR();
  SCHED0();

#pragma unroll 2
  for (int i = 0; i < 16; i++) {
    const int cur = i & 1, nxt = cur ^ 1;
    const long kt0 = (long)i * 64, kt1 = kt0 + 64;
    const bool last = (i == 15);

    // ---- phase A: hi-pass (Ah x B[cur]) ----
    // stage Al(i) FIRST (oldest in queue -> drained by vmcnt(4))
#pragma unroll
    for (int r = 0; r < 4; r++) STG(Alg, AlT, r, kt0);
    if (!last) {
#pragma unroll
      for (int r = 0; r < 4; r++) STG(Bg, Bs2[nxt], r, kt1);
    }
#pragma unroll
    for (int ks = 0; ks < 2; ks++) {
      const int kx = ((ks * 4 + q) ^ mx7) * 8;
      half8 a[8];
#pragma unroll
      for (int nf = 0; nf < 4; nf++)
        b[ks][nf] = *(const half8*)(&Bs2[cur][(bBase + nf * 16 + m16) * 64 + kx]);
#pragma unroll
      for (int mf = 0; mf < 8; mf++)
        a[mf] = *(const half8*)(&AhT[(aBase + mf * 16 + m16) * 64 + kx]);
      __builtin_amdgcn_s_setprio(1);
#pragma unroll
      for (int mf = 0; mf < 8; mf++)
#pragma unroll
        for (int nf = 0; nf < 4; nf++)
          acc[mf][nf] = __builtin_amdgcn_mfma_f32_16x16x32_f16(
              a[mf], b[ks][nf], acc[mf][nf], 0, 0, 0);
      __builtin_amdgcn_s_setprio(0);
    }
    if (!last) {
      asm volatile("s_waitcnt vmcnt(4)" ::: "memory");  // Al(i) landed
    } else {
      asm volatile("s_waitcnt vmcnt(0)" ::: "memory");
    }
    BAR();
    SCHED0();

    // ---- phase B: lo-pass (Al x cached b) ----
    if (!last) {
#pragma unroll
      for (int r = 0; r < 4; r++) STG(Ahg, AhT, r, kt1);
    }
#pragma unroll
    for (int ks = 0; ks < 2; ks++) {
      const int kx = ((ks * 4 + q) ^ mx7) * 8;
      half8 a[8];
#pragma unroll
      for (int mf = 0; mf < 8; mf++)
        a[mf] = *(const half8*)(&AlT[(aBase + mf * 16 + m16) * 64 + kx]);
      __builtin_amdgcn_s_setprio(1);
#pragma unroll
      for (int mf = 0; mf < 8; mf++)
#pragma unroll
        for (int nf = 0; nf < 4; nf++)
          acc[mf][nf] = __builtin_amdgcn_mfma_f32_16x16x32_f16(
              a[mf], b[ks][nf], acc[mf][nf], 0, 0, 0);
      __builtin_amdgcn_s_setprio(0);
    }
    // aged drain: B(i+1) ~1.5 phases old, Ah(i+1) ~0.9 phase old
    asm volatile("s_waitcnt vmcnt(0)" ::: "memory");
    BAR();
    SCHED0();
  }
#undef STG

  // C/D frag: col = lane&15, row = quad*4 + reg  [m89/m91 verified]
#pragma unroll
  for (int mf = 0; mf < 8; mf++)
#pragma unroll
    for (int r = 0; r < 4; r++) {
      const long rr = rowBase + wr * 128 + mf * 16 + q * 4 + r;
#pragma unroll
      for (int nf = 0; nf < 4; nf++)
        S[rr * D_FF + colBase + wc * 64 + nf * 16 + m16] = acc[mf][nf][r];
    }
}

// ---------------------------------------------------------------------------
// GEMM2: O[4096,1024] fp32 += P[4096, lda 8192] @ WT[1024,4096]^T  (R11)
// 256x256xBK64 full dbuf, 512 thr, wave 128x64, split-K=4, T3-minimal:
// STG next (8 gld) BEFORE compute; vmcnt(0) after 64 MFMA (aged ~1 phase);
// one barrier per K-iter. Grid 4x16x4 = 256 = 1 block/CU. Atomics to O.
// ---------------------------------------------------------------------------
__global__ __launch_bounds__(512, 2) void gemm2_kernel(
    const _Float16* __restrict__ P, const _Float16* __restrict__ WT,
    float* __restrict__ O) {
  constexpr int K = D_FF, LDA = 2 * D_FF, KSPLIT = 1024;
  __shared__ _Float16 As2[2][256 * 64];  // 64 KB
  __shared__ _Float16 Bs2[2][256 * 64];  // 64 KB
  const int tid = threadIdx.x;
  const int lane = tid & 63, wave = tid >> 6;

  // XCD-chunked bijective swizzle (nwg = 4*16*4 = 256)
  const int bid = ((blockIdx.z * 16 + blockIdx.y) << 2) | blockIdx.x;
  const int lg = ((bid & 7) << 5) | (bid >> 3);
  const int bx = lg & 3, by = (lg >> 2) & 15, bz = lg >> 6;

  const long rowBase = (long)by * 256;
  const long colBase = (long)bx * 256;
  const int k0 = bz * KSPLIT;

  const int srow = tid >> 3;
  const int scol = ((tid & 7) ^ (srow & 7)) * 8;
  const _Float16* Ag = P + (rowBase + srow) * (long)LDA + scol;
  const _Float16* Bg = WT + (colBase + srow) * (long)K + scol;
  const int dstOff = tid * 8;

  const int wr = wave >> 2, wc = wave & 3;  // wave tile: 128 rows x 64 cols
  const int m16 = lane & 15, q = lane >> 4, mx7 = m16 & 7;
  const int aBase = wr * 128, bBase = wc * 64;

  floatx4 acc[8][4] = {};

#define STG2(G, T, R, KT, STRIDE) \
  gld_lds16((G) + (long)(R)*64 * (STRIDE) + (KT), &(T)[(R)*4096 + dstOff]);

  // ---- prologue ----
#pragma unroll
  for (int r = 0; r < 4; r++) STG2(Ag, As2[0], r, k0, LDA);
#pragma unroll
  for (int r = 0; r < 4; r++) STG2(Bg, Bs2[0], r, k0, K);
  asm volatile("s_waitcnt vmcnt(0)" ::: "memory");
  BAR();
  SCHED0();

#pragma unroll 2
  for (int t = 0; t < 16; t++) {
    const int cur = t & 1, nxt = cur ^ 1;
    const long ktn = (long)k0 + (t + 1) * 64;
    const bool last = (t == 15);

    if (!last) {
#pragma unroll
      for (int r = 0; r < 4; r++) STG2(Ag, As2[nxt], r, ktn, LDA);
#pragma unroll
      for (int r = 0; r < 4; r++) STG2(Bg, Bs2[nxt], r, ktn, K);
    }
#pragma unroll
    for (int ks = 0; ks < 2; ks++) {
      const int kx = ((ks * 4 + q) ^ mx7) * 8;
      half8 a[8], b[4];
#pragma unroll
      for (int nf = 0; nf < 4; nf++)
        b[nf] = *(const half8*)(&Bs2[cur][(bBase + nf * 16 + m16) * 64 + kx]);
#pragma unroll
      for (int mf = 0; mf < 8; mf++)
        a[mf] = *(const half8*)(&As2[cur][(aBase + mf * 16 + m16) * 64 + kx]);
      __builtin_amdgcn_s_setprio(1);
#pragma unroll
      for (int mf = 0; mf < 8; mf++)
#pragma unroll
        for (int nf = 0; nf < 4; nf++)
          acc[mf][nf] = __builtin_amdgcn_mfma_f32_16x16x32_f16(
              a[mf], b[nf], acc[mf][nf], 0, 0, 0);
      __builtin_amdgcn_s_setprio(0);
    }
    // aged drain: staged loads had the full MFMA cluster (~2500cyc) to land
    asm volatile("s_waitcnt vmcnt(0)" ::: "memory");
    BAR();
    SCHED0();
  }
#undef STG2
#undef BAR
#undef SCHED0

#pragma unroll
  for (int mf = 0; mf < 8; mf++)
#pragma unroll
    for (int r = 0; r < 4; r++) {
      const long rr = rowBase + wr * 128 + mf * 16 + q * 4 + r;
#pragma unroll
      for (int nf = 0; nf < 4; nf++)
        unsafeAtomicAdd(&O[rr * D_MODEL + colBase + wc * 64 + nf * 16 + m16],
                        acc[mf][nf][r]);
    }
}

// ---------------------------------------------------------------------------
// softmax over rows of 4096: fp32 S in, fp16 P out in-place at row start.
// ---------------------------------------------------------------------------
__global__ __launch_bounds__(256) void softmax_kernel(float* __restrict__ S) {
  float* s = S + (long)blockIdx.x * D_FF;
  const int t = threadIdx.x;
  const int lane = t & 63, wave = t >> 6;
  __shared__ float redm[4], redl[4];

  float v[16];
  float mx = -3.4e38f;
#pragma unroll
  for (int seg = 0; seg < 4; seg++) {
    const float4 f = *(const float4*)(s + seg * 1024 + t * 4);
    v[seg * 4 + 0] = f.x; v[seg * 4 + 1] = f.y;
    v[seg * 4 + 2] = f.z; v[seg * 4 + 3] = f.w;
  }
#pragma unroll
  for (int j = 0; j < 16; j++) mx = fmaxf(mx, v[j]);
#pragma unroll
  for (int off = 32; off >= 1; off >>= 1) mx = fmaxf(mx, __shfl_xor(mx, off));
  if (lane == 0) redm[wave] = mx;
  __syncthreads();
  const float m = fmaxf(fmaxf(redm[0], redm[1]), fmaxf(redm[2], redm[3]));

  float sum = 0.f;
#pragma unroll
  for (int j = 0; j < 16; j++) {
    v[j] = __expf(v[j] - m);
    sum += v[j];
  }
#pragma unroll
  for (int off = 32; off >= 1; off >>= 1) sum += __shfl_xor(sum, off);
  if (lane == 0) redl[wave] = sum;
  __syncthreads();
  const float inv = 1.f / (redl[0] + redl[1] + redl[2] + redl[3]);

  _Float16* p = (_Float16*)s;  // all reads of this row completed above
#pragma unroll
  for (int seg = 0; seg < 4; seg++) {
    half4 h;
#pragma unroll
    for (int j = 0; j < 4; j++) h[j] = (_Float16)(v[seg * 4 + j] * inv);
    *(half4*)(p + seg * 1024 + t * 4) = h;
  }
}

// ---------------------------------------------------------------------------
extern "C" void kernel_launch(void* const* d_in, const int* in_sizes, int n_in,
                              void* d_out, int out_size, void* d_ws, size_t ws_size,
                              hipStream_t stream) {
  const float* x = (const float*)d_in[0];  // [16384,1024] fp32
  const float* w = (const float*)d_in[1];  // [4096,1024] fp32
  float* out = (float*)d_out;              // [16384,1024] fp32

  // ws layout: xh 32Mi | xl 32Mi | wh 8Mi | wl 8Mi | wT 8Mi | S 64Mi = 152Mi
  const size_t NEED = 152ull << 20;
  if (ws_size < NEED) return;

  char* ws = (char*)d_ws;
  _Float16* xh = (_Float16*)(ws);
  _Float16* xl = (_Float16*)(ws + (32ull << 20));
  _Float16* wh = (_Float16*)(ws + (64ull << 20));
  _Float16* wl = (_Float16*)(ws + (72ull << 20));  // written, unused (R5)
  _Float16* wT = (_Float16*)(ws + (80ull << 20));
  float*    S  = (float*)   (ws + (88ull << 20));

  // gemm2 accumulates via atomics -> zero d_out first (graph-capture safe)
  hipMemsetAsync(d_out, 0, (size_t)M_ROWS * D_MODEL * sizeof(float), stream);

  hipLaunchKernelGGL(rmsnorm_split_kernel, dim3(MB_X + MB_W), dim3(256), 0,
                     stream, x, xh, xl, w, wh, wl);
  hipLaunchKernelGGL(transpose_kernel, dim3(D_MODEL / 32, D_FF / 32), dim3(256),
                     0, stream, w, wT);

  for (int c = 0; c < M_ROWS / MC; c++) {
    const long ro = (long)c * MC;
    hipLaunchKernelGGL(gemm1_kernel, dim3(16, 16), dim3(512), 0,
                       stream, xh + ro * D_MODEL, xl + ro * D_MODEL, wh, S);
    hipLaunchKernelGGL(softmax_kernel, dim3(MC), dim3(256), 0, stream, S);
    hipLaunchKernelGGL(gemm2_kernel, dim3(4, 16, 4), dim3(512), 0,
                       stream, (const _Float16*)S, wT, out + ro * D_MODEL);
  }
}

// Round 6
// 701.727 us; speedup vs baseline: 1.2240x; 1.2240x over previous
//
#include <hip/hip_runtime.h>
#include <hip/hip_fp16.h>

// ---------------------------------------------------------------------------
// VQFFN1: out = softmax(rmsnorm(x) @ rmsnorm(w)^T) @ w
//   x: [16384,1024] fp32   w: [4096,1024] fp32   out: [16384,1024] fp32
// fp32 scores; GEMM2 plain fp16 + split-K + f32 HW atomics.
// R2: XOR-swizzled LDS (bank conflicts 3.8e7 -> 0).
// R5: S = (xh + xl) @ wh^T; shared WH tile + b-frags across both passes.
// R8: gemm2 BK 64->128: 650us; gemm1 at MfmaUtil 43%.
// R9/R10/R11 FAILED: all fine-phase / 1-block-per-CU (128KB LDS) schedules
//     landed at 26-40% MfmaUtil. Common factor: losing the 2-blocks/CU
//     implicit overlap (m114) costs more than any intra-block pipelining
//     recovers. Scheduling lane closed; chassis reverted to R8.
// R12: 32x32x16 MFMA on the R8 chassis, both GEMMs. Same reads, same
//     staging/swizzle (frag row&7 == (lane&31)&7 so the XOR store side is
//     unchanged), HALF the MFMA issue slots, better pipe rate (2382 vs
//     2075 uB). C/D: col=lane&31, row=(reg&3)+8*(reg>>2)+4*(lane>>5)
//     [m74/m101 verified].
// ---------------------------------------------------------------------------

#define D_MODEL 1024
#define D_FF    4096
#define M_ROWS  16384
#define MC      4096

typedef _Float16 half8 __attribute__((ext_vector_type(8)));
typedef _Float16 half4 __attribute__((ext_vector_type(4)));
typedef float    floatx16 __attribute__((ext_vector_type(16)));

// async global->LDS, 16B/lane; LDS dst = wave-uniform base + lane*16 (m97)
__device__ __forceinline__ void gld_lds16(const void* g, void* l) {
  __builtin_amdgcn_global_load_lds(
      (const __attribute__((address_space(1))) void*)g,
      (__attribute__((address_space(3))) void*)l, 16, 0, 0);
}

// ---------------------------------------------------------------------------
// rmsnorm (fp32 in) + hi/lo fp16 split. One wave per row of 1024.
// ---------------------------------------------------------------------------
#define MB_X (M_ROWS / 4)
#define MB_W (D_FF / 4)
__global__ __launch_bounds__(256) void rmsnorm_split_kernel(
    const float* __restrict__ X, _Float16* __restrict__ XH,
    _Float16* __restrict__ XL, const float* __restrict__ W,
    _Float16* __restrict__ WH, _Float16* __restrict__ WL) {
  const int lane = threadIdx.x & 63;
  const bool isW = blockIdx.x >= MB_X;
  const long row = (long)(isW ? blockIdx.x - MB_X : blockIdx.x) * 4 +
                   (threadIdx.x >> 6);
  const float* x = (isW ? W : X) + row * D_MODEL;
  _Float16* YH = (isW ? WH : XH) + row * D_MODEL;
  _Float16* YL = (isW ? WL : XL) + row * D_MODEL;

  float v[16];
  float ss = 0.f;
#pragma unroll
  for (int s = 0; s < 4; s++) {
    const float4 f = *(const float4*)(x + s * 256 + lane * 4);
    v[s * 4 + 0] = f.x; v[s * 4 + 1] = f.y;
    v[s * 4 + 2] = f.z; v[s * 4 + 3] = f.w;
    ss += f.x * f.x + f.y * f.y + f.z * f.z + f.w * f.w;
  }
#pragma unroll
  for (int off = 32; off >= 1; off >>= 1) ss += __shfl_xor(ss, off);
  const float inv = rsqrtf(ss * (1.0f / D_MODEL) + 1e-6f);
#pragma unroll
  for (int s = 0; s < 4; s++) {
    half4 h, l;
#pragma unroll
    for (int j = 0; j < 4; j++) {
      const float t = v[s * 4 + j] * inv;
      const _Float16 hi = (_Float16)t;
      h[j] = hi;
      l[j] = (_Float16)(t - (float)hi);
    }
    *(half4*)(YH + s * 256 + lane * 4) = h;
    *(half4*)(YL + s * 256 + lane * 4) = l;
  }
}

// ---------------------------------------------------------------------------
// transpose w [4096,1024] fp32 -> wT [1024,4096] fp16 (unnormalized, GEMM2 B)
// ---------------------------------------------------------------------------
__global__ __launch_bounds__(256) void transpose_kernel(
    const float* __restrict__ W, _Float16* __restrict__ WT) {
  __shared__ _Float16 tile[32][33];
  const int tx = threadIdx.x & 31;
  const int ty = threadIdx.x >> 5;  // 0..7
  const int d0 = blockIdx.x * 32;
  const int c0 = blockIdx.y * 32;
#pragma unroll
  for (int i = 0; i < 32; i += 8)
    tile[ty + i][tx] = (_Float16)W[(long)(c0 + ty + i) * D_MODEL + d0 + tx];
  __syncthreads();
#pragma unroll
  for (int i = 0; i < 32; i += 8)
    WT[(long)(d0 + ty + i) * D_FF + c0 + tx] = tile[tx][ty + i];
}

// ---------------------------------------------------------------------------
// GEMM K-loops: m97 structure + R2 XOR swizzle (single LDS buffer).
// LDS slot (row, s) holds global data (row, s ^ (row&7)); swizzle applied by
// permuting the *global source* lane address. Fragment reads XOR the k-slot
// with (lane&31)&7 -> ~conflict-free ds_read_b128.
// 32x32x16 fragments: A row = lane&31, k = (lane>>5)*8 + j  (slot ks*2+hi5);
// B col = lane&31, same k.  C/D: col=lane&31, row=(r&3)+8*(r>>2)+4*(lane>>5).
// ---------------------------------------------------------------------------

// GEMM1: S[4096,4096] fp32 = (xh + xl) @ wh^T over K=1024.
// 128x256 block tile, 4 waves, wave tile 64x128 = 2x4 32x32 tiles;
// per ks (K=16): b[4] + a_hi[2] reads, 8 MFMA, a_lo[2], 8 MFMA.
__global__ __launch_bounds__(256, 2) void gemm1_kernel(
    const _Float16* __restrict__ XH, const _Float16* __restrict__ XL,
    const _Float16* __restrict__ WH, float* __restrict__ S) {
  constexpr int BK = 64;
  __shared__ _Float16 Ah[128 * BK];  // xh tile (16 KB)
  __shared__ _Float16 Al[128 * BK];  // xl tile (16 KB)
  __shared__ _Float16 Bs[256 * BK];  // wh tile (32 KB)
  const int tid = threadIdx.x;
  const int wave = tid >> 6, lane = tid & 63;
  const long rowBase = (long)blockIdx.y * 128;
  const long colBase = (long)blockIdx.x * 256;
  const int srow = lane >> 3;
  const int scol = ((lane & 7) ^ (lane >> 3)) * 8;  // XOR-swizzled source col
  const _Float16* AgH = XH + (rowBase + wave * 32 + srow) * (long)D_MODEL + scol;
  const _Float16* AgL = XL + (rowBase + wave * 32 + srow) * (long)D_MODEL + scol;
  const _Float16* Bg  = WH + (colBase + wave * 64 + srow) * (long)D_MODEL + scol;
  const int ldsOffA = wave * 2048 + lane * 8;  // 32 rows/wave
  const int ldsOffB = wave * 4096 + lane * 8;  // 64 rows/wave
  const int wr = wave >> 1, wc = wave & 1;
  const int l31 = lane & 31, hi5 = lane >> 5;
  const int sx = l31 & 7;  // fragment-row & 7 (tile offsets are mult. of 32)

  floatx16 acc[2][4] = {};

  for (int kt = 0; kt < D_MODEL; kt += BK) {
#pragma unroll
    for (int i = 0; i < 4; i++) {
      gld_lds16(AgH + i * 8 * D_MODEL + kt, Ah + ldsOffA + i * 512);
      gld_lds16(AgL + i * 8 * D_MODEL + kt, Al + ldsOffA + i * 512);
    }
#pragma unroll
    for (int i = 0; i < 8; i++)
      gld_lds16(Bg + i * 8 * D_MODEL + kt, Bs + ldsOffB + i * 512);
    __syncthreads();
#pragma unroll
    for (int ks = 0; ks < 4; ks++) {  // K = 16 each
      const int kx = ((ks * 2 + hi5) ^ sx) * 8;
      half8 b[4], a[2];
#pragma unroll
      for (int ni = 0; ni < 4; ni++)
        b[ni] = *(const half8*)(&Bs[(wc * 128 + ni * 32 + l31) * BK + kx]);
#pragma unroll
      for (int mi = 0; mi < 2; mi++)
        a[mi] = *(const half8*)(&Ah[(wr * 64 + mi * 32 + l31) * BK + kx]);
      __builtin_amdgcn_s_setprio(1);
#pragma unroll
      for (int mi = 0; mi < 2; mi++)
#pragma unroll
        for (int ni = 0; ni < 4; ni++)
          acc[mi][ni] = __builtin_amdgcn_mfma_f32_32x32x16_f16(
              a[mi], b[ni], acc[mi][ni], 0, 0, 0);
      __builtin_amdgcn_s_setprio(0);
#pragma unroll
      for (int mi = 0; mi < 2; mi++)
        a[mi] = *(const half8*)(&Al[(wr * 64 + mi * 32 + l31) * BK + kx]);
      __builtin_amdgcn_s_setprio(1);
#pragma unroll
      for (int mi = 0; mi < 2; mi++)
#pragma unroll
        for (int ni = 0; ni < 4; ni++)
          acc[mi][ni] = __builtin_amdgcn_mfma_f32_32x32x16_f16(
              a[mi], b[ni], acc[mi][ni], 0, 0, 0);
      __builtin_amdgcn_s_setprio(0);
    }
    __syncthreads();
  }

  // C/D 32x32: col = lane&31, row = (r&3) + 8*(r>>2) + 4*hi5  [m74/m101]
#pragma unroll
  for (int mi = 0; mi < 2; mi++)
#pragma unroll
    for (int r = 0; r < 16; r++) {
      const long rr =
          rowBase + wr * 64 + mi * 32 + (r & 3) + 8 * (r >> 2) + 4 * hi5;
#pragma unroll
      for (int ni = 0; ni < 4; ni++)
        S[rr * D_FF + colBase + wc * 128 + ni * 32 + l31] = acc[mi][ni][r];
    }
}

// GEMM2: O[4096,1024] fp32 += P[4096, lda 8192] @ WT[1024,4096]^T
// 128x128 tile, BK=128 (R8), split-K=2, HW f32 atomics into pre-zeroed O.
// Wave tile 64x64 = 2x2 32x32 tiles; 8 ksteps of K=16, 4 MFMA each.
__global__ __launch_bounds__(256, 2) void gemm2_kernel(
    const _Float16* __restrict__ P, const _Float16* __restrict__ WT,
    float* __restrict__ O) {
  constexpr int BK = 128, K = D_FF, LDA = 2 * D_FF, KSPLIT = 2048;
  __shared__ _Float16 As[128 * BK];  // 32 KB
  __shared__ _Float16 Bs[128 * BK];  // 32 KB
  const int tid = threadIdx.x;
  const int wave = tid >> 6, lane = tid & 63;

  // XCD-chunked bijective swizzle (nwg = 8*32*2 = 512, %8 == 0)
  const int bid = ((blockIdx.z * 32 + blockIdx.y) << 3) | blockIdx.x;
  const int swz = ((bid & 7) << 6) | (bid >> 3);
  const int bx = swz & 7;          // col-block   0..7
  const int by = (swz >> 3) & 31;  // row-block   0..31
  const int bz = swz >> 8;         // K-split     0..1

  const long rowBase = (long)by * 128;
  const long colBase = (long)bx * 128;
  const int k0 = bz * KSPLIT;

  // staging geometry: 1 gld_lds16 instr = 1KB = 4 rows x 256B
  const int srow4 = lane >> 4;              // 0..3
  const int slotE = (lane & 15) ^ srow4;    // even-i swizzled 16B slot
  const int slotO = slotE ^ 4;              // odd-i  (row&7 gains +4)
  const _Float16* AgE = P + (rowBase + wave * 32 + srow4) * (long)LDA + slotE * 8;
  const _Float16* AgO = P + (rowBase + wave * 32 + srow4) * (long)LDA + slotO * 8;
  const _Float16* BgE = WT + (colBase + wave * 32 + srow4) * (long)K + slotE * 8;
  const _Float16* BgO = WT + (colBase + wave * 32 + srow4) * (long)K + slotO * 8;
  _Float16* AsW = As + wave * 4096 + lane * 8;  // 32 rows/wave * 128
  _Float16* BsW = Bs + wave * 4096 + lane * 8;
  const int wr = wave >> 1, wc = wave & 1;
  const int l31 = lane & 31, hi5 = lane >> 5;
  const int sx = l31 & 7;

  floatx16 acc[2][2] = {};

  for (int kt = k0; kt < k0 + KSPLIT; kt += BK) {
#pragma unroll
    for (int i = 0; i < 8; i++) {
      const _Float16* ag = (i & 1) ? AgO : AgE;
      const _Float16* bg = (i & 1) ? BgO : BgE;
      gld_lds16(ag + (long)i * 4 * LDA + kt, AsW + i * 512);
      gld_lds16(bg + (long)i * 4 * K + kt, BsW + i * 512);
    }
    __syncthreads();
#pragma unroll
    for (int ks = 0; ks < 8; ks++) {  // K = 16 each
      const int kx = ((ks * 2 + hi5) ^ sx) * 8;  // slot 0..15, XOR low 3 bits
      half8 a[2], b[2];
#pragma unroll
      for (int mi = 0; mi < 2; mi++)
        a[mi] = *(const half8*)(&As[(wr * 64 + mi * 32 + l31) * BK + kx]);
#pragma unroll
      for (int ni = 0; ni < 2; ni++)
        b[ni] = *(const half8*)(&Bs[(wc * 64 + ni * 32 + l31) * BK + kx]);
      __builtin_amdgcn_s_setprio(1);
#pragma unroll
      for (int mi = 0; mi < 2; mi++)
#pragma unroll
        for (int ni = 0; ni < 2; ni++)
          acc[mi][ni] = __builtin_amdgcn_mfma_f32_32x32x16_f16(
              a[mi], b[ni], acc[mi][ni], 0, 0, 0);
      __builtin_amdgcn_s_setprio(0);
    }
    __syncthreads();
  }

#pragma unroll
  for (int mi = 0; mi < 2; mi++)
#pragma unroll
    for (int r = 0; r < 16; r++) {
      const long rr =
          rowBase + wr * 64 + mi * 32 + (r & 3) + 8 * (r >> 2) + 4 * hi5;
#pragma unroll
      for (int ni = 0; ni < 2; ni++)
        unsafeAtomicAdd(&O[rr * D_MODEL + colBase + wc * 64 + ni * 32 + l31],
                        acc[mi][ni][r]);
    }
}

// ---------------------------------------------------------------------------
// softmax over rows of 4096: fp32 S in, fp16 P out in-place at row start.
// ---------------------------------------------------------------------------
__global__ __launch_bounds__(256) void softmax_kernel(float* __restrict__ S) {
  float* s = S + (long)blockIdx.x * D_FF;
  const int t = threadIdx.x;
  const int lane = t & 63, wave = t >> 6;
  __shared__ float redm[4], redl[4];

  float v[16];
  float mx = -3.4e38f;
#pragma unroll
  for (int seg = 0; seg < 4; seg++) {
    const float4 f = *(const float4*)(s + seg * 1024 + t * 4);
    v[seg * 4 + 0] = f.x; v[seg * 4 + 1] = f.y;
    v[seg * 4 + 2] = f.z; v[seg * 4 + 3] = f.w;
  }
#pragma unroll
  for (int j = 0; j < 16; j++) mx = fmaxf(mx, v[j]);
#pragma unroll
  for (int off = 32; off >= 1; off >>= 1) mx = fmaxf(mx, __shfl_xor(mx, off));
  if (lane == 0) redm[wave] = mx;
  __syncthreads();
  const float m = fmaxf(fmaxf(redm[0], redm[1]), fmaxf(redm[2], redm[3]));

  float sum = 0.f;
#pragma unroll
  for (int j = 0; j < 16; j++) {
    v[j] = __expf(v[j] - m);
    sum += v[j];
  }
#pragma unroll
  for (int off = 32; off >= 1; off >>= 1) sum += __shfl_xor(sum, off);
  if (lane == 0) redl[wave] = sum;
  __syncthreads();
  const float inv = 1.f / (redl[0] + redl[1] + redl[2] + redl[3]);

  _Float16* p = (_Float16*)s;  // all reads of this row completed above
#pragma unroll
  for (int seg = 0; seg < 4; seg++) {
    half4 h;
#pragma unroll
    for (int j = 0; j < 4; j++) h[j] = (_Float16)(v[seg * 4 + j] * inv);
    *(half4*)(p + seg * 1024 + t * 4) = h;
  }
}

// ---------------------------------------------------------------------------
extern "C" void kernel_launch(void* const* d_in, const int* in_sizes, int n_in,
                              void* d_out, int out_size, void* d_ws, size_t ws_size,
                              hipStream_t stream) {
  const float* x = (const float*)d_in[0];  // [16384,1024] fp32
  const float* w = (const float*)d_in[1];  // [4096,1024] fp32
  float* out = (float*)d_out;              // [16384,1024] fp32

  // ws layout: xh 32Mi | xl 32Mi | wh 8Mi | wl 8Mi | wT 8Mi | S 64Mi = 152Mi
  const size_t NEED = 152ull << 20;
  if (ws_size < NEED) return;

  char* ws = (char*)d_ws;
  _Float16* xh = (_Float16*)(ws);
  _Float16* xl = (_Float16*)(ws + (32ull << 20));
  _Float16* wh = (_Float16*)(ws + (64ull << 20));
  _Float16* wl = (_Float16*)(ws + (72ull << 20));  // written, unused (R5)
  _Float16* wT = (_Float16*)(ws + (80ull << 20));
  float*    S  = (float*)   (ws + (88ull << 20));

  // gemm2 accumulates via atomics -> zero d_out first (graph-capture safe)
  hipMemsetAsync(d_out, 0, (size_t)M_ROWS * D_MODEL * sizeof(float), stream);

  hipLaunchKernelGGL(rmsnorm_split_kernel, dim3(MB_X + MB_W), dim3(256), 0,
                     stream, x, xh, xl, w, wh, wl);
  hipLaunchKernelGGL(transpose_kernel, dim3(D_MODEL / 32, D_FF / 32), dim3(256),
                     0, stream, w, wT);

  for (int c = 0; c < M_ROWS / MC; c++) {
    const long ro = (long)c * MC;
    hipLaunchKernelGGL(gemm1_kernel, dim3(D_FF / 256, MC / 128), dim3(256), 0,
                       stream, xh + ro * D_MODEL, xl + ro * D_MODEL, wh, S);
    hipLaunchKernelGGL(softmax_kernel, dim3(MC), dim3(256), 0, stream, S);
    hipLaunchKernelGGL(gemm2_kernel, dim3(D_MODEL / 128, MC / 128, 2),
                       dim3(256), 0, stream, (const _Float16*)S, wT,
                       out + ro * D_MODEL);
  }
}

// Round 7
// 570.894 us; speedup vs baseline: 1.5045x; 1.2292x over previous
//
#include <hip/hip_runtime.h>
#include <hip/hip_fp16.h>

// ---------------------------------------------------------------------------
// VQFFN1: out = softmax(rmsnorm(x) @ rmsnorm(w)^T) @ w
//   x: [16384,1024] fp32   w: [4096,1024] fp32   out: [16384,1024] fp32
// fp32 scores; GEMM2 plain fp16 + split-K + f32 HW atomics.
// R2: XOR-swizzled LDS (bank conflicts 3.8e7 -> 0).
// R5: S = (xh + xl) @ wh^T (xh@wl dropped; absmax unchanged 6.1e-4).
// R8: gemm2 BK 64->128: 650us; gemm1 at MfmaUtil 43%.
// R9/R10/R11 FAILED: fine-phase / 1-block-per-CU schedules all lost the
//     2-blocks/CU implicit overlap (m114); 26-40% MfmaUtil. Lane closed.
// R12 NEUTRAL: 32x32x16 on both GEMMs: 4.19e6 bank conflicts (32 rows onto
//     8 16B-slots at BK=64 is inherently 4-way). Conflict-free 32x32 needs
//     BK=128 rows -> 1 block/CU LDS -> death zone. Lane closed.
// R13: ALGORITHMIC: drop xl@wh -> single-pass fp16 gemm1 on the R8 chassis.
//     Rationale: absmax has been bit-identical (6.103516e-4) across every
//     round incl. R5's symmetric drop of xh@wl -> output error is dominated
//     by P->fp16 quantization, not score error. Halves gemm1 MFMA work;
//     rmsnorm no longer writes xl/wl. gemm2 = R8 verbatim.
// ---------------------------------------------------------------------------

#define D_MODEL 1024
#define D_FF    4096
#define M_ROWS  16384
#define MC      4096

typedef _Float16 half8 __attribute__((ext_vector_type(8)));
typedef _Float16 half4 __attribute__((ext_vector_type(4)));
typedef float    floatx4 __attribute__((ext_vector_type(4)));

// async global->LDS, 16B/lane; LDS dst = wave-uniform base + lane*16 (m97)
__device__ __forceinline__ void gld_lds16(const void* g, void* l) {
  __builtin_amdgcn_global_load_lds(
      (const __attribute__((address_space(1))) void*)g,
      (__attribute__((address_space(3))) void*)l, 16, 0, 0);
}

// ---------------------------------------------------------------------------
// rmsnorm (fp32 in) -> fp16. One wave per row of 1024.
// ---------------------------------------------------------------------------
#define MB_X (M_ROWS / 4)
#define MB_W (D_FF / 4)
__global__ __launch_bounds__(256) void rmsnorm_kernel(
    const float* __restrict__ X, _Float16* __restrict__ XH,
    const float* __restrict__ W, _Float16* __restrict__ WH) {
  const int lane = threadIdx.x & 63;
  const bool isW = blockIdx.x >= MB_X;
  const long row = (long)(isW ? blockIdx.x - MB_X : blockIdx.x) * 4 +
                   (threadIdx.x >> 6);
  const float* x = (isW ? W : X) + row * D_MODEL;
  _Float16* YH = (isW ? WH : XH) + row * D_MODEL;

  float v[16];
  float ss = 0.f;
#pragma unroll
  for (int s = 0; s < 4; s++) {
    const float4 f = *(const float4*)(x + s * 256 + lane * 4);
    v[s * 4 + 0] = f.x; v[s * 4 + 1] = f.y;
    v[s * 4 + 2] = f.z; v[s * 4 + 3] = f.w;
    ss += f.x * f.x + f.y * f.y + f.z * f.z + f.w * f.w;
  }
#pragma unroll
  for (int off = 32; off >= 1; off >>= 1) ss += __shfl_xor(ss, off);
  const float inv = rsqrtf(ss * (1.0f / D_MODEL) + 1e-6f);
#pragma unroll
  for (int s = 0; s < 4; s++) {
    half4 h;
#pragma unroll
    for (int j = 0; j < 4; j++) h[j] = (_Float16)(v[s * 4 + j] * inv);
    *(half4*)(YH + s * 256 + lane * 4) = h;
  }
}

// ---------------------------------------------------------------------------
// transpose w [4096,1024] fp32 -> wT [1024,4096] fp16 (unnormalized, GEMM2 B)
// ---------------------------------------------------------------------------
__global__ __launch_bounds__(256) void transpose_kernel(
    const float* __restrict__ W, _Float16* __restrict__ WT) {
  __shared__ _Float16 tile[32][33];
  const int tx = threadIdx.x & 31;
  const int ty = threadIdx.x >> 5;  // 0..7
  const int d0 = blockIdx.x * 32;
  const int c0 = blockIdx.y * 32;
#pragma unroll
  for (int i = 0; i < 32; i += 8)
    tile[ty + i][tx] = (_Float16)W[(long)(c0 + ty + i) * D_MODEL + d0 + tx];
  __syncthreads();
#pragma unroll
  for (int i = 0; i < 32; i += 8)
    WT[(long)(d0 + ty + i) * D_FF + c0 + tx] = tile[tx][ty + i];
}

// ---------------------------------------------------------------------------
// GEMM K-loops: m97 structure + R2 XOR swizzle (single LDS buffer).
// LDS slot (row, s) holds global data (row, s ^ (row&7)); swizzle applied by
// permuting the *global source* lane address. Fragment reads XOR the k-slot
// with m16&7 -> conflict-free ds_read_b128 (measured 0).
// ---------------------------------------------------------------------------

// GEMM1: S[4096,4096] fp32 = xh @ wh^T over K=1024.  (single-pass, R13)
// 128x256 block tile, 4 waves, wave tile 64x128 (acc[4][8]); per ks:
// 12 LDS reads feed 32 MFMA. LDS 48KB -> 2 blocks/CU (m114 overlap).
__global__ __launch_bounds__(256, 2) void gemm1_kernel(
    const _Float16* __restrict__ XH, const _Float16* __restrict__ WH,
    float* __restrict__ S) {
  constexpr int BK = 64;
  __shared__ _Float16 Ah[128 * BK];  // xh tile (16 KB)
  __shared__ _Float16 Bs[256 * BK];  // wh tile (32 KB)
  const int tid = threadIdx.x;
  const int wave = tid >> 6, lane = tid & 63;
  const long rowBase = (long)blockIdx.y * 128;
  const long colBase = (long)blockIdx.x * 256;
  const int srow = lane >> 3;
  const int scol = ((lane & 7) ^ (lane >> 3)) * 8;  // XOR-swizzled source col
  const _Float16* AgH = XH + (rowBase + wave * 32 + srow) * (long)D_MODEL + scol;
  const _Float16* Bg  = WH + (colBase + wave * 64 + srow) * (long)D_MODEL + scol;
  const int ldsOffA = wave * 2048 + lane * 8;  // 32 rows/wave
  const int ldsOffB = wave * 4096 + lane * 8;  // 64 rows/wave
  const int wr = wave >> 1, wc = wave & 1;
  const int m16 = lane & 15, q = lane >> 4;
  const int mx7 = m16 & 7;

  floatx4 acc[4][8] = {};

  for (int kt = 0; kt < D_MODEL; kt += BK) {
#pragma unroll
    for (int i = 0; i < 4; i++)
      gld_lds16(AgH + i * 8 * D_MODEL + kt, Ah + ldsOffA + i * 512);
#pragma unroll
    for (int i = 0; i < 8; i++)
      gld_lds16(Bg + i * 8 * D_MODEL + kt, Bs + ldsOffB + i * 512);
    __syncthreads();
#pragma unroll
    for (int ks = 0; ks < 2; ks++) {
      const int kx = ((ks * 4 + q) ^ mx7) * 8;
      half8 b[8], a[4];
#pragma unroll
      for (int ni = 0; ni < 8; ni++)
        b[ni] = *(const half8*)(&Bs[(wc * 128 + ni * 16 + m16) * BK + kx]);
#pragma unroll
      for (int mi = 0; mi < 4; mi++)
        a[mi] = *(const half8*)(&Ah[(wr * 64 + mi * 16 + m16) * BK + kx]);
      __builtin_amdgcn_s_setprio(1);
#pragma unroll
      for (int mi = 0; mi < 4; mi++)
#pragma unroll
        for (int ni = 0; ni < 8; ni++)
          acc[mi][ni] = __builtin_amdgcn_mfma_f32_16x16x32_f16(
              a[mi], b[ni], acc[mi][ni], 0, 0, 0);
      __builtin_amdgcn_s_setprio(0);
    }
    __syncthreads();
  }

  // C/D frag: col = lane&15, row = quad*4 + reg  [m89/m91 verified]
#pragma unroll
  for (int mi = 0; mi < 4; mi++)
#pragma unroll
    for (int r = 0; r < 4; r++) {
      const long rr = rowBase + wr * 64 + mi * 16 + q * 4 + r;
#pragma unroll
      for (int ni = 0; ni < 8; ni++)
        S[rr * D_FF + colBase + wc * 128 + ni * 16 + m16] = acc[mi][ni][r];
    }
}

// GEMM2: O[4096,1024] fp32 += P[4096, lda 8192] @ WT[1024,4096]^T
// 128x128 tile, BK=128 (R8), split-K=2, HW f32 atomics into pre-zeroed O.
// Staging: instr i covers 4 rows (lane>>4); row&7 = (i&1)*4 + (lane>>4), so
// even/odd i use two pre-swizzled source pointers (slot ^4 flip).
__global__ __launch_bounds__(256, 2) void gemm2_kernel(
    const _Float16* __restrict__ P, const _Float16* __restrict__ WT,
    float* __restrict__ O) {
  constexpr int BK = 128, K = D_FF, LDA = 2 * D_FF, KSPLIT = 2048;
  __shared__ _Float16 As[128 * BK];  // 32 KB
  __shared__ _Float16 Bs[128 * BK];  // 32 KB
  const int tid = threadIdx.x;
  const int wave = tid >> 6, lane = tid & 63;

  // XCD-chunked bijective swizzle (nwg = 8*32*2 = 512, %8 == 0)
  const int bid = ((blockIdx.z * 32 + blockIdx.y) << 3) | blockIdx.x;
  const int swz = ((bid & 7) << 6) | (bid >> 3);
  const int bx = swz & 7;          // col-block   0..7
  const int by = (swz >> 3) & 31;  // row-block   0..31
  const int bz = swz >> 8;         // K-split     0..1

  const long rowBase = (long)by * 128;
  const long colBase = (long)bx * 128;
  const int k0 = bz * KSPLIT;

  // staging geometry: 1 gld_lds16 instr = 1KB = 4 rows x 256B
  const int srow4 = lane >> 4;              // 0..3
  const int slotE = (lane & 15) ^ srow4;    // even-i swizzled 16B slot
  const int slotO = slotE ^ 4;              // odd-i  (row&7 gains +4)
  const _Float16* AgE = P + (rowBase + wave * 32 + srow4) * (long)LDA + slotE * 8;
  const _Float16* AgO = P + (rowBase + wave * 32 + srow4) * (long)LDA + slotO * 8;
  const _Float16* BgE = WT + (colBase + wave * 32 + srow4) * (long)K + slotE * 8;
  const _Float16* BgO = WT + (colBase + wave * 32 + srow4) * (long)K + slotO * 8;
  _Float16* AsW = As + wave * 4096 + lane * 8;  // 32 rows/wave * 128
  _Float16* BsW = Bs + wave * 4096 + lane * 8;
  const int wr = wave >> 1, wc = wave & 1;
  const int m16 = lane & 15, q = lane >> 4;
  const int mx7 = m16 & 7;

  floatx4 acc[4][4] = {};

  for (int kt = k0; kt < k0 + KSPLIT; kt += BK) {
#pragma unroll
    for (int i = 0; i < 8; i++) {
      const _Float16* ag = (i & 1) ? AgO : AgE;
      const _Float16* bg = (i & 1) ? BgO : BgE;
      gld_lds16(ag + (long)i * 4 * LDA + kt, AsW + i * 512);
      gld_lds16(bg + (long)i * 4 * K + kt, BsW + i * 512);
    }
    __syncthreads();
#pragma unroll
    for (int ks = 0; ks < 4; ks++) {
      const int kx = ((ks * 4 + q) ^ mx7) * 8;
      half8 a[4], b[4];
#pragma unroll
      for (int mi = 0; mi < 4; mi++)
        a[mi] = *(const half8*)(&As[(wr * 64 + mi * 16 + m16) * BK + kx]);
#pragma unroll
      for (int ni = 0; ni < 4; ni++)
        b[ni] = *(const half8*)(&Bs[(wc * 64 + ni * 16 + m16) * BK + kx]);
      __builtin_amdgcn_s_setprio(1);
#pragma unroll
      for (int mi = 0; mi < 4; mi++)
#pragma unroll
        for (int ni = 0; ni < 4; ni++)
          acc[mi][ni] = __builtin_amdgcn_mfma_f32_16x16x32_f16(
              a[mi], b[ni], acc[mi][ni], 0, 0, 0);
      __builtin_amdgcn_s_setprio(0);
    }
    __syncthreads();
  }

#pragma unroll
  for (int mi = 0; mi < 4; mi++)
#pragma unroll
    for (int r = 0; r < 4; r++) {
      const long rr = rowBase + wr * 64 + mi * 16 + q * 4 + r;
#pragma unroll
      for (int ni = 0; ni < 4; ni++)
        unsafeAtomicAdd(&O[rr * D_MODEL + colBase + wc * 64 + ni * 16 + m16],
                        acc[mi][ni][r]);
    }
}

// ---------------------------------------------------------------------------
// softmax over rows of 4096: fp32 S in, fp16 P out in-place at row start.
// ---------------------------------------------------------------------------
__global__ __launch_bounds__(256) void softmax_kernel(float* __restrict__ S) {
  float* s = S + (long)blockIdx.x * D_FF;
  const int t = threadIdx.x;
  const int lane = t & 63, wave = t >> 6;
  __shared__ float redm[4], redl[4];

  float v[16];
  float mx = -3.4e38f;
#pragma unroll
  for (int seg = 0; seg < 4; seg++) {
    const float4 f = *(const float4*)(s + seg * 1024 + t * 4);
    v[seg * 4 + 0] = f.x; v[seg * 4 + 1] = f.y;
    v[seg * 4 + 2] = f.z; v[seg * 4 + 3] = f.w;
  }
#pragma unroll
  for (int j = 0; j < 16; j++) mx = fmaxf(mx, v[j]);
#pragma unroll
  for (int off = 32; off >= 1; off >>= 1) mx = fmaxf(mx, __shfl_xor(mx, off));
  if (lane == 0) redm[wave] = mx;
  __syncthreads();
  const float m = fmaxf(fmaxf(redm[0], redm[1]), fmaxf(redm[2], redm[3]));

  float sum = 0.f;
#pragma unroll
  for (int j = 0; j < 16; j++) {
    v[j] = __expf(v[j] - m);
    sum += v[j];
  }
#pragma unroll
  for (int off = 32; off >= 1; off >>= 1) sum += __shfl_xor(sum, off);
  if (lane == 0) redl[wave] = sum;
  __syncthreads();
  const float inv = 1.f / (redl[0] + redl[1] + redl[2] + redl[3]);

  _Float16* p = (_Float16*)s;  // all reads of this row completed above
#pragma unroll
  for (int seg = 0; seg < 4; seg++) {
    half4 h;
#pragma unroll
    for (int j = 0; j < 4; j++) h[j] = (_Float16)(v[seg * 4 + j] * inv);
    *(half4*)(p + seg * 1024 + t * 4) = h;
  }
}

// ---------------------------------------------------------------------------
extern "C" void kernel_launch(void* const* d_in, const int* in_sizes, int n_in,
                              void* d_out, int out_size, void* d_ws, size_t ws_size,
                              hipStream_t stream) {
  const float* x = (const float*)d_in[0];  // [16384,1024] fp32
  const float* w = (const float*)d_in[1];  // [4096,1024] fp32
  float* out = (float*)d_out;              // [16384,1024] fp32

  // ws layout: xh 32Mi | (unused 32Mi) | wh 8Mi | (unused 8Mi) | wT 8Mi |
  //            S 64Mi = 152Mi  (offsets kept from prior rounds)
  const size_t NEED = 152ull << 20;
  if (ws_size < NEED) return;

  char* ws = (char*)d_ws;
  _Float16* xh = (_Float16*)(ws);
  _Float16* wh = (_Float16*)(ws + (64ull << 20));
  _Float16* wT = (_Float16*)(ws + (80ull << 20));
  float*    S  = (float*)   (ws + (88ull << 20));

  // gemm2 accumulates via atomics -> zero d_out first (graph-capture safe)
  hipMemsetAsync(d_out, 0, (size_t)M_ROWS * D_MODEL * sizeof(float), stream);

  hipLaunchKernelGGL(rmsnorm_kernel, dim3(MB_X + MB_W), dim3(256), 0,
                     stream, x, xh, w, wh);
  hipLaunchKernelGGL(transpose_kernel, dim3(D_MODEL / 32, D_FF / 32), dim3(256),
                     0, stream, w, wT);

  for (int c = 0; c < M_ROWS / MC; c++) {
    const long ro = (long)c * MC;
    hipLaunchKernelGGL(gemm1_kernel, dim3(D_FF / 256, MC / 128), dim3(256), 0,
                       stream, xh + ro * D_MODEL, wh, S);
    hipLaunchKernelGGL(softmax_kernel, dim3(MC), dim3(256), 0, stream, S);
    hipLaunchKernelGGL(gemm2_kernel, dim3(D_MODEL / 128, MC / 128, 2),
                       dim3(256), 0, stream, (const _Float16*)S, wT,
                       out + ro * D_MODEL);
  }
}